// Round 20
// baseline (172.928 us; speedup 1.0000x reference)
//
#include <hip/hip_runtime.h>

#define BATCH 8
#define NROW  2048
#define NF    64
#define JSPLIT 4
#define JPB   (NROW / JSPLIT)               // 512 k per z-slice
#define CHUNK 64
#define TOT   ((size_t)BATCH * NROW * NF)   // 1048576

typedef float    f32x4 __attribute__((ext_vector_type(4)));
typedef _Float16 f16x8 __attribute__((ext_vector_type(8)));
typedef unsigned short u16x8 __attribute__((ext_vector_type(8)));

union fragh { u16x8 u; f16x8 h; };
union hbits { _Float16 h; unsigned short u; };

#define ASCALE 4096.0f     // 2^12
#define XSCALE 2048.0f     // 2^11
#define THRESH 4194304.0   // 0.5 * 2^23

#define AS1 __attribute__((address_space(1)))
#define AS3 __attribute__((address_space(3)))

__device__ __forceinline__ void gld16u(const unsigned short* g, unsigned short* l) {
  __builtin_amdgcn_global_load_lds((const AS1 void*)g, (AS3 void*)l, 16, 0, 0);
}

// ---- pass 1: transpose x, scale, split into 2 f16 levels (b = flat&7 == XCD)
__global__ __launch_bounds__(256, 4)
void prep_x(const float* __restrict__ xg, unsigned short* __restrict__ xs) {
  __shared__ float t[64][65];
  const int flat = blockIdx.x;
  const int b  = flat & 7;
  const int j0 = (flat >> 3) * 64;
  const int l  = threadIdx.x & 63;
  const int g  = threadIdx.x >> 6;
  const float* src = xg + ((size_t)b * NROW + j0) * NF;
#pragma unroll
  for (int k = 0; k < 16; ++k) {
    const int j = g * 16 + k;
    t[j][l] = src[(size_t)j * NF + l];
  }
  __syncthreads();
#pragma unroll
  for (int k = 0; k < 16; ++k) {
    const int f = g * 16 + k;
    const float v = t[l][f] * XSCALE;
    hbits b0, b1;
    b0.h = (_Float16)v;
    const float r = v - (float)b0.h;      // exact
    b1.h = (_Float16)r;
    const size_t o = ((size_t)b * NF + f) * NROW + j0 + l;
    xs[o]       = b0.u;
    xs[o + TOT] = b1.u;
  }
}

// split 8 scaled f32 -> 2 f16 fragments (RNE; residual exact) [proven r15-r18]
__device__ __forceinline__ void split8h(const f32x4 q0, const f32x4 q1,
                                        fragh* Af) {
  float av[8];
  *(f32x4*)&av[0] = q0;
  *(f32x4*)&av[4] = q1;
  f16x8 h0, h1;
#pragma unroll
  for (int e = 0; e < 8; ++e) {
    const float v = av[e] * ASCALE;
    const _Float16 b0 = (_Float16)v;
    const float r = v - (float)b0;        // exact
    h0[e] = b0;
    h1[e] = (_Float16)r;
  }
  Af[0].h = h0; Af[1].h = h1;
}

// ---- pass 2: 2-level f16 MFMA GEMM (r18 structure) + fused last-block
//      combine. All 4 z-blocks of tile (b,bx) share flat&7 = b = XCD ->
//      partials stay in one L2. Writer: stores -> threadfence -> atomicAdd;
//      last arriver (old==3) re-reads 4 partials (L2-hot) and thresholds.
template <bool DIRECT>
__global__ __launch_bounds__(512, 4)
void gemm_mfma(const float* __restrict__ ag, const unsigned short* __restrict__ xs,
               float* __restrict__ outg, float* __restrict__ wp,
               unsigned* __restrict__ cnt) {
  __shared__ __align__(16) unsigned short sB[2][2 * 64 * CHUNK];   // 2 x 16KB
  __shared__ int lastFlag;

  const int tid  = threadIdx.x;
  const int ln   = tid & 63;
  const int wv   = tid >> 6;          // 0..7
  const int ln15 = ln & 15;
  const int g    = ln >> 4;
  const int bkey = ln15 & 7;

  const int flat = blockIdx.x;
  const int b    = flat & 7;                      // batch == XCD
  const int rr   = flat >> 3;
  const int bx   = rr & 15;                       // 16 row-tiles of 128
  const int z    = DIRECT ? 0 : ((rr >> 4) & 3);
  const int i0   = bx * 128;
  const int jb   = z * JPB;
  const int nch  = (DIRECT ? NROW : JPB) / CHUNK;   // 32 or 8

  const float* aA =
      ag + ((size_t)b * NROW + i0 + wv * 16 + ln15) * NROW + jb + g * 8;
  const unsigned short* xB = xs + (size_t)b * NF * NROW;

  auto stageB = [&](int buf, int j0) {
#pragma unroll
    for (int lvl = 0; lvl < 2; ++lvl) {
      const int n = tid >> 3;
      const int q = (tid & 7) ^ (n & 7);
      gld16u(xB + (size_t)lvl * TOT + (size_t)n * NROW + j0 + q * 8,
             &sB[buf][0] + (lvl * 512 + wv * 64) * 8);
    }
  };

  double macc[4][4];
#pragma unroll
  for (int i = 0; i < 4; ++i)
#pragma unroll
    for (int j = 0; j < 4; ++j) macc[i][j] = 0.0;

  constexpr int AI[4] = {1, 1, 0, 0};
  constexpr int BI[4] = {1, 0, 1, 0};

  stageB(0, jb);
  f32x4 A0 = *(const f32x4*)(aA);
  f32x4 A1 = *(const f32x4*)(aA + 4);
  f32x4 A2 = *(const f32x4*)(aA + 32);
  f32x4 A3 = *(const f32x4*)(aA + 36);

#pragma unroll 1
  for (int t = 0; t < nch; ++t) {
    __syncthreads();
    if (t + 1 < nch) stageB((t + 1) & 1, jb + (t + 1) * CHUNK);
    const int tn = (t + 1 < nch) ? (t + 1) : t;
    const float* aNxt = aA + (size_t)tn * CHUNK;
    f32x4 N0 = *(const f32x4*)(aNxt);
    f32x4 N1 = *(const f32x4*)(aNxt + 4);
    f32x4 N2 = *(const f32x4*)(aNxt + 32);
    f32x4 N3 = *(const f32x4*)(aNxt + 36);

    const unsigned short* sBb = &sB[t & 1][0];
    f32x4 c[4];
#pragma unroll
    for (int nt = 0; nt < 4; ++nt) c[nt] = (f32x4){0.f, 0.f, 0.f, 0.f};

#pragma unroll
    for (int sub = 0; sub < 2; ++sub) {
      fragh Af[2];
      split8h(sub ? A2 : A0, sub ? A3 : A1, Af);

      const int bq = (sub * 4 + g) ^ bkey;
#pragma unroll
      for (int ng = 0; ng < 2; ++ng) {
        fragh Bv[2][2];
#pragma unroll
        for (int nn = 0; nn < 2; ++nn) {
          const int ncol = (ng * 2 + nn) * 16 + ln15;
#pragma unroll
          for (int lvl = 0; lvl < 2; ++lvl)
            Bv[nn][lvl].u =
                *(const u16x8*)(sBb + lvl * 4096 + ncol * 64 + bq * 8);
        }
#pragma unroll
        for (int term = 0; term < 4; ++term)
#pragma unroll
          for (int nn = 0; nn < 2; ++nn) {
            const int nt = ng * 2 + nn;
            c[nt] = __builtin_amdgcn_mfma_f32_16x16x32_f16(
                Af[AI[term]].h, Bv[nn][BI[term]].h, c[nt], 0, 0, 0);
          }
      }
    }
    A0 = N0; A1 = N1; A2 = N2; A3 = N3;

#pragma unroll
    for (int nt = 0; nt < 4; ++nt) {
      macc[nt][0] += (double)c[nt].x;
      macc[nt][1] += (double)c[nt].y;
      macc[nt][2] += (double)c[nt].z;
      macc[nt][3] += (double)c[nt].w;
    }
  }

  if (DIRECT) {
#pragma unroll
    for (int nt = 0; nt < 4; ++nt)
#pragma unroll
      for (int r = 0; r < 4; ++r)
        outg[((size_t)b * NROW + i0 + wv * 16 + g * 4 + r) * NF + nt * 16 + ln15] =
            (macc[nt][r] > THRESH) ? 1.0f : 0.0f;
    return;
  }

  // ---- write partials ----
  float* wb = wp + (size_t)z * TOT;
#pragma unroll
  for (int nt = 0; nt < 4; ++nt)
#pragma unroll
    for (int r = 0; r < 4; ++r)
      wb[((size_t)b * NROW + i0 + wv * 16 + g * 4 + r) * NF + nt * 16 + ln15] =
          (float)macc[nt][r];

  // ---- last-block-per-tile combine (same-XCD L2; no spinning) ----
  __threadfence();                       // partial stores visible before count
  if (tid == 0) {
    const unsigned old = __hip_atomic_fetch_add(
        &cnt[b * 16 + bx], 1u, __ATOMIC_ACQ_REL, __HIP_MEMORY_SCOPE_AGENT);
    lastFlag = (old == JSPLIT - 1);
  }
  __syncthreads();
  if (!lastFlag) return;

  // tile = 128 rows x 64 cols = 8192 floats; 512 thr x 4 x 4 iters
  const size_t base = ((size_t)b * NROW + i0) * NF;
#pragma unroll
  for (int k = 0; k < 4; ++k) {
    const size_t e = base + (size_t)k * 2048 + (size_t)tid * 4;
    f32x4 p0 = *(const f32x4*)(wp + e);
    f32x4 p1 = *(const f32x4*)(wp + e + TOT);
    f32x4 p2 = *(const f32x4*)(wp + e + 2 * TOT);
    f32x4 p3 = *(const f32x4*)(wp + e + 3 * TOT);
    f32x4 o;
    o.x = (((double)p0.x + p1.x + p2.x + p3.x) > THRESH) ? 1.0f : 0.0f;
    o.y = (((double)p0.y + p1.y + p2.y + p3.y) > THRESH) ? 1.0f : 0.0f;
    o.z = (((double)p0.z + p1.z + p2.z + p3.z) > THRESH) ? 1.0f : 0.0f;
    o.w = (((double)p0.w + p1.w + p2.w + p3.w) > THRESH) ? 1.0f : 0.0f;
    *(f32x4*)(outg + e) = o;
  }
}

extern "C" void kernel_launch(void* const* d_in, const int* in_sizes, int n_in,
                              void* d_out, int out_size, void* d_ws, size_t ws_size,
                              hipStream_t stream) {
  const float* x = (const float*)d_in[0];
  const float* a = (const float*)d_in[1];
  float* out = (float*)d_out;
  unsigned short* xs = (unsigned short*)d_ws;                 // 4 MB
  float* wp  = (float*)((char*)d_ws + 2 * TOT * sizeof(unsigned short));
  unsigned* cnt = (unsigned*)((char*)d_ws + 2 * TOT * sizeof(unsigned short)
                              + (size_t)JSPLIT * TOT * sizeof(float));

  const size_t need = 2 * TOT * sizeof(unsigned short)
                    + (size_t)JSPLIT * TOT * sizeof(float) + 512;  // ~20 MB
  prep_x<<<dim3(256), dim3(256), 0, stream>>>(x, xs);
  if (ws_size >= need) {
    hipMemsetAsync(cnt, 0, 512, stream);
    gemm_mfma<false><<<dim3(JSPLIT * BATCH * (NROW / 128)), dim3(512), 0, stream>>>(
        a, xs, out, wp, cnt);
  } else {
    gemm_mfma<true><<<dim3(BATCH * (NROW / 128)), dim3(512), 0, stream>>>(
        a, xs, out, nullptr, nullptr);
  }
}

// Round 21
// 45.172 us; speedup vs baseline: 3.8282x; 3.8282x over previous
//
#include <hip/hip_runtime.h>

#define BATCH 8
#define NROW  2048
#define NF    64
#define JSPLIT 8
#define JPB   (NROW / JSPLIT)               // 256 k per z-slice
#define CHUNK 64
#define TOT   ((size_t)BATCH * NROW * NF)   // 1048576

typedef float    f32x4 __attribute__((ext_vector_type(4)));
typedef _Float16 f16x8 __attribute__((ext_vector_type(8)));
typedef unsigned short u16x8 __attribute__((ext_vector_type(8)));

union fragh { u16x8 u; f16x8 h; };
union hbits { _Float16 h; unsigned short u; };

#define ASCALE 4096.0f     // 2^12  (a in [0,1) -> [0,4096): no f16 denormals)
#define XSCALE 2048.0f     // 2^11  (|x|max ~5.5 -> ~11k < 65504)
#define THRESH 4194304.0   // 0.5 * 2^23 (product scale)

#define AS1 __attribute__((address_space(1)))
#define AS3 __attribute__((address_space(3)))

__device__ __forceinline__ void gld16u(const unsigned short* g, unsigned short* l) {
  __builtin_amdgcn_global_load_lds((const AS1 void*)g, (AS3 void*)l, 16, 0, 0);
}

// ---- pass 1: transpose x, scale, split into 2 f16 levels (b = flat&7 == XCD)
__global__ __launch_bounds__(256, 4)
void prep_x(const float* __restrict__ xg, unsigned short* __restrict__ xs) {
  __shared__ float t[64][65];
  const int flat = blockIdx.x;
  const int b  = flat & 7;
  const int j0 = (flat >> 3) * 64;
  const int l  = threadIdx.x & 63;
  const int g  = threadIdx.x >> 6;
  const float* src = xg + ((size_t)b * NROW + j0) * NF;
#pragma unroll
  for (int k = 0; k < 16; ++k) {
    const int j = g * 16 + k;
    t[j][l] = src[(size_t)j * NF + l];
  }
  __syncthreads();
#pragma unroll
  for (int k = 0; k < 16; ++k) {
    const int f = g * 16 + k;
    const float v = t[l][f] * XSCALE;
    hbits b0, b1;
    b0.h = (_Float16)v;
    const float r = v - (float)b0.h;      // exact
    b1.h = (_Float16)r;
    const size_t o = ((size_t)b * NF + f) * NROW + j0 + l;
    xs[o]       = b0.u;
    xs[o + TOT] = b1.u;
  }
}

// split 8 scaled f32 -> 2 f16 fragments (RNE; residual exact) [proven r15-r18]
__device__ __forceinline__ void split8h(const f32x4 q0, const f32x4 q1,
                                        fragh* Af) {
  float av[8];
  *(f32x4*)&av[0] = q0;
  *(f32x4*)&av[4] = q1;
  f16x8 h0, h1;
#pragma unroll
  for (int e = 0; e < 8; ++e) {
    const float v = av[e] * ASCALE;
    const _Float16 b0 = (_Float16)v;
    const float r = v - (float)b0;        // exact
    h0[e] = b0;
    h1[e] = (_Float16)r;
  }
  Af[0].h = h0; Af[1].h = h1;
}

// ---- pass 2: 2-level f16 MFMA GEMM, 8-wave blocks (r18 structure),
//      JSPLIT=8 -> grid 1024 = 4 blocks/CU (32 waves/CU cap, vs r18's 16).
//      Per-chunk stage:compute ratio and all addressing byte-identical r18.
//      No device-scope fences/atomics anywhere (r17/r20 lesson).
template <bool DIRECT>
__global__ __launch_bounds__(512, 4)
void gemm_mfma(const float* __restrict__ ag, const unsigned short* __restrict__ xs,
               float* __restrict__ outg, float* __restrict__ wp) {
  __shared__ __align__(16) unsigned short sB[2][2 * 64 * CHUNK];   // 2 x 16KB

  const int tid  = threadIdx.x;
  const int ln   = tid & 63;
  const int wv   = tid >> 6;          // 0..7
  const int ln15 = ln & 15;
  const int g    = ln >> 4;
  const int bkey = ln15 & 7;

  const int flat = blockIdx.x;
  const int b    = flat & 7;                      // batch == XCD
  const int rr   = flat >> 3;
  const int bx   = rr & 15;                       // 16 row-tiles of 128
  const int z    = DIRECT ? 0 : ((rr >> 4) & 7);
  const int i0   = bx * 128;
  const int jb   = z * JPB;
  const int nch  = (DIRECT ? NROW : JPB) / CHUNK;   // 32 or 4

  const float* aA =
      ag + ((size_t)b * NROW + i0 + wv * 16 + ln15) * NROW + jb + g * 8;
  const unsigned short* xB = xs + (size_t)b * NF * NROW;

  auto stageB = [&](int buf, int j0) {
#pragma unroll
    for (int lvl = 0; lvl < 2; ++lvl) {
      const int n = tid >> 3;
      const int q = (tid & 7) ^ (n & 7);
      gld16u(xB + (size_t)lvl * TOT + (size_t)n * NROW + j0 + q * 8,
             &sB[buf][0] + (lvl * 512 + wv * 64) * 8);
    }
  };

  double macc[4][4];
#pragma unroll
  for (int i = 0; i < 4; ++i)
#pragma unroll
    for (int j = 0; j < 4; ++j) macc[i][j] = 0.0;

  constexpr int AI[4] = {1, 1, 0, 0};
  constexpr int BI[4] = {1, 0, 1, 0};

  stageB(0, jb);
  f32x4 A0 = *(const f32x4*)(aA);          // sub0: k = g*8
  f32x4 A1 = *(const f32x4*)(aA + 4);
  f32x4 A2 = *(const f32x4*)(aA + 32);     // sub1: k = 32 + g*8
  f32x4 A3 = *(const f32x4*)(aA + 36);

#pragma unroll 1
  for (int t = 0; t < nch; ++t) {
    __syncthreads();                  // stage(t) visible; buf^1 free
    if (t + 1 < nch) stageB((t + 1) & 1, jb + (t + 1) * CHUNK);
    const int tn = (t + 1 < nch) ? (t + 1) : t;
    const float* aNxt = aA + (size_t)tn * CHUNK;
    f32x4 N0 = *(const f32x4*)(aNxt);
    f32x4 N1 = *(const f32x4*)(aNxt + 4);
    f32x4 N2 = *(const f32x4*)(aNxt + 32);
    f32x4 N3 = *(const f32x4*)(aNxt + 36);

    const unsigned short* sBb = &sB[t & 1][0];
    f32x4 c[4];
#pragma unroll
    for (int nt = 0; nt < 4; ++nt) c[nt] = (f32x4){0.f, 0.f, 0.f, 0.f};

#pragma unroll
    for (int sub = 0; sub < 2; ++sub) {
      fragh Af[2];
      split8h(sub ? A2 : A0, sub ? A3 : A1, Af);

      const int bq = (sub * 4 + g) ^ bkey;
#pragma unroll
      for (int ng = 0; ng < 2; ++ng) {
        fragh Bv[2][2];
#pragma unroll
        for (int nn = 0; nn < 2; ++nn) {
          const int ncol = (ng * 2 + nn) * 16 + ln15;
#pragma unroll
          for (int lvl = 0; lvl < 2; ++lvl)
            Bv[nn][lvl].u =
                *(const u16x8*)(sBb + lvl * 4096 + ncol * 64 + bq * 8);
        }
#pragma unroll
        for (int term = 0; term < 4; ++term)
#pragma unroll
          for (int nn = 0; nn < 2; ++nn) {
            const int nt = ng * 2 + nn;
            c[nt] = __builtin_amdgcn_mfma_f32_16x16x32_f16(
                Af[AI[term]].h, Bv[nn][BI[term]].h, c[nt], 0, 0, 0);
          }
      }
    }
    A0 = N0; A1 = N1; A2 = N2; A3 = N3;

#pragma unroll
    for (int nt = 0; nt < 4; ++nt) {
      macc[nt][0] += (double)c[nt].x;
      macc[nt][1] += (double)c[nt].y;
      macc[nt][2] += (double)c[nt].z;
      macc[nt][3] += (double)c[nt].w;
    }
  }

  // epilogue: D row = g*4 + r (within 16-tile), col = nt*16 + ln15
  if (DIRECT) {
#pragma unroll
    for (int nt = 0; nt < 4; ++nt)
#pragma unroll
      for (int r = 0; r < 4; ++r)
        outg[((size_t)b * NROW + i0 + wv * 16 + g * 4 + r) * NF + nt * 16 + ln15] =
            (macc[nt][r] > THRESH) ? 1.0f : 0.0f;
  } else {
    float* wb = wp + (size_t)z * TOT;
#pragma unroll
    for (int nt = 0; nt < 4; ++nt)
#pragma unroll
      for (int r = 0; r < 4; ++r)
        wb[((size_t)b * NROW + i0 + wv * 16 + g * 4 + r) * NF + nt * 16 + ln15] =
            (float)macc[nt][r];
  }
}

// ---- pass 3: reduce JSPLIT partials in f64, threshold ----
// grid 1024, b = flat&7 == XCD: reads the partial slices its own XCD's gemm
// blocks just wrote (8 x 0.5 MB = 4 MB/XCD, L2-resident).
__global__ __launch_bounds__(256)
void combine_thresh(const float* __restrict__ wsv, float* __restrict__ outg) {
  const int flat = blockIdx.x;
  const int b    = flat & 7;
  const int idx  = flat >> 3;                    // 0..127
  const size_t e = ((size_t)b << 17) + (size_t)idx * 1024 + (size_t)threadIdx.x * 4;
  double s0 = 0.0, s1 = 0.0, s2 = 0.0, s3 = 0.0;
#pragma unroll
  for (int z = 0; z < JSPLIT; ++z) {
    f32x4 p = *(const f32x4*)(wsv + e + (size_t)z * TOT);
    s0 += (double)p.x; s1 += (double)p.y; s2 += (double)p.z; s3 += (double)p.w;
  }
  f32x4 o;
  o.x = (s0 > THRESH) ? 1.0f : 0.0f;
  o.y = (s1 > THRESH) ? 1.0f : 0.0f;
  o.z = (s2 > THRESH) ? 1.0f : 0.0f;
  o.w = (s3 > THRESH) ? 1.0f : 0.0f;
  *(f32x4*)(outg + e) = o;
}

extern "C" void kernel_launch(void* const* d_in, const int* in_sizes, int n_in,
                              void* d_out, int out_size, void* d_ws, size_t ws_size,
                              hipStream_t stream) {
  const float* x = (const float*)d_in[0];
  const float* a = (const float*)d_in[1];
  float* out = (float*)d_out;
  unsigned short* xs = (unsigned short*)d_ws;                 // 4 MB
  float* wp = (float*)((char*)d_ws + 2 * TOT * sizeof(unsigned short));

  prep_x<<<dim3(256), dim3(256), 0, stream>>>(x, xs);

  const size_t need = 2 * TOT * sizeof(unsigned short)
                    + (size_t)JSPLIT * TOT * sizeof(float);   // 36 MB
  if (ws_size >= need) {
    gemm_mfma<false><<<dim3(JSPLIT * BATCH * (NROW / 128)), dim3(512), 0, stream>>>(
        a, xs, out, wp);
    combine_thresh<<<dim3((unsigned)(TOT / 1024)), dim3(256), 0, stream>>>(wp, out);
  } else {
    gemm_mfma<true><<<dim3(BATCH * (NROW / 128)), dim3(512), 0, stream>>>(
        a, xs, out, nullptr);
  }
}

// Round 22
// 40.181 us; speedup vs baseline: 4.3038x; 1.1242x over previous
//
#include <hip/hip_runtime.h>

#define BATCH 8
#define NROW  2048
#define NF    64
#define JSPLIT 4
#define JPB   (NROW / JSPLIT)               // 512 k per z-slice
#define CHUNK 64
#define TOT   ((size_t)BATCH * NROW * NF)   // 1048576

typedef float    f32x4 __attribute__((ext_vector_type(4)));
typedef _Float16 f16x8 __attribute__((ext_vector_type(8)));
typedef unsigned short u16x8 __attribute__((ext_vector_type(8)));

union fragh { u16x8 u; f16x8 h; };
union hbits { _Float16 h; unsigned short u; };

#define ASCALE 4096.0f     // 2^12  (a in [0,1) -> [0,4096): no f16 denormals)
#define XSCALE 2048.0f     // 2^11  (|x|max ~5.5 -> ~11k < 65504)
#define THRESH 4194304.0   // 0.5 * 2^23 (product scale)

#define AS1 __attribute__((address_space(1)))
#define AS3 __attribute__((address_space(3)))

__device__ __forceinline__ void gld16u(const unsigned short* g, unsigned short* l) {
  __builtin_amdgcn_global_load_lds((const AS1 void*)g, (AS3 void*)l, 16, 0, 0);
}

// ---- pass 1: transpose x, scale, split into 2 f16 levels (b = flat&7 == XCD)
__global__ __launch_bounds__(256, 4)
void prep_x(const float* __restrict__ xg, unsigned short* __restrict__ xs) {
  __shared__ float t[64][65];
  const int flat = blockIdx.x;
  const int b  = flat & 7;
  const int j0 = (flat >> 3) * 64;
  const int l  = threadIdx.x & 63;
  const int g  = threadIdx.x >> 6;
  const float* src = xg + ((size_t)b * NROW + j0) * NF;
#pragma unroll
  for (int k = 0; k < 16; ++k) {
    const int j = g * 16 + k;
    t[j][l] = src[(size_t)j * NF + l];
  }
  __syncthreads();
#pragma unroll
  for (int k = 0; k < 16; ++k) {
    const int f = g * 16 + k;
    const float v = t[l][f] * XSCALE;
    hbits b0, b1;
    b0.h = (_Float16)v;
    const float r = v - (float)b0.h;      // exact
    b1.h = (_Float16)r;
    const size_t o = ((size_t)b * NF + f) * NROW + j0 + l;
    xs[o]       = b0.u;
    xs[o + TOT] = b1.u;
  }
}

// split 8 scaled f32 -> 2 f16 fragments (RNE; residual exact) [proven r15-r18]
__device__ __forceinline__ void split8h(const f32x4 q0, const f32x4 q1,
                                        fragh* Af) {
  float av[8];
  *(f32x4*)&av[0] = q0;
  *(f32x4*)&av[4] = q1;
  f16x8 h0, h1;
#pragma unroll
  for (int e = 0; e < 8; ++e) {
    const float v = av[e] * ASCALE;
    const _Float16 b0 = (_Float16)v;
    const float r = v - (float)b0;        // exact
    h0[e] = b0;
    h1[e] = (_Float16)r;
  }
  Af[0].h = h0; Af[1].h = h1;
}

// ---- pass 2: 2-level f16 MFMA GEMM, 8-wave blocks (r18 structure, the
//      session's best: 39.9 us). Block: 512 thr = 8 waves, 128 rows x 64
//      cols; wave wv -> rows i0+wv*16..+16. Per chunk (64 k): ONE 16KB
//      B-stage serves 128 rows, per wave 2 subs x {split8h, 8 ds_read_b128,
//      16 MFMA}, one barrier, one f64 fold. B LDS dbuf 2x16KB, store octet
//      (s&7)^(n&7), read octet (sub*4+g)^(ncol&7) -> conflict-free.
//      A: global->reg prefetch-1 (coalesced). b = flat&7 == XCD.
//      No device-scope fences/atomics (r17/r20: ~100us poison on gfx950).
template <bool DIRECT>
__global__ __launch_bounds__(512, 4)
void gemm_mfma(const float* __restrict__ ag, const unsigned short* __restrict__ xs,
               float* __restrict__ outg, float* __restrict__ wp) {
  __shared__ __align__(16) unsigned short sB[2][2 * 64 * CHUNK];   // 2 x 16KB

  const int tid  = threadIdx.x;
  const int ln   = tid & 63;
  const int wv   = tid >> 6;          // 0..7
  const int ln15 = ln & 15;
  const int g    = ln >> 4;
  const int bkey = ln15 & 7;

  const int flat = blockIdx.x;
  const int b    = flat & 7;                      // batch == XCD
  const int rr   = flat >> 3;
  const int bx   = rr & 15;                       // 16 row-tiles of 128
  const int z    = DIRECT ? 0 : ((rr >> 4) & 3);
  const int i0   = bx * 128;
  const int jb   = z * JPB;
  const int nch  = (DIRECT ? NROW : JPB) / CHUNK;   // 32 or 8

  const float* aA =
      ag + ((size_t)b * NROW + i0 + wv * 16 + ln15) * NROW + jb + g * 8;
  const unsigned short* xB = xs + (size_t)b * NF * NROW;

  auto stageB = [&](int buf, int j0) {
#pragma unroll
    for (int lvl = 0; lvl < 2; ++lvl) {
      const int n = tid >> 3;
      const int q = (tid & 7) ^ (n & 7);
      gld16u(xB + (size_t)lvl * TOT + (size_t)n * NROW + j0 + q * 8,
             &sB[buf][0] + (lvl * 512 + wv * 64) * 8);
    }
  };

  double macc[4][4];
#pragma unroll
  for (int i = 0; i < 4; ++i)
#pragma unroll
    for (int j = 0; j < 4; ++j) macc[i][j] = 0.0;

  constexpr int AI[4] = {1, 1, 0, 0};
  constexpr int BI[4] = {1, 0, 1, 0};

  stageB(0, jb);
  f32x4 A0 = *(const f32x4*)(aA);          // sub0: k = g*8
  f32x4 A1 = *(const f32x4*)(aA + 4);
  f32x4 A2 = *(const f32x4*)(aA + 32);     // sub1: k = 32 + g*8
  f32x4 A3 = *(const f32x4*)(aA + 36);

#pragma unroll 1
  for (int t = 0; t < nch; ++t) {
    __syncthreads();                  // stage(t) visible; buf^1 free
    if (t + 1 < nch) stageB((t + 1) & 1, jb + (t + 1) * CHUNK);
    const int tn = (t + 1 < nch) ? (t + 1) : t;
    const float* aNxt = aA + (size_t)tn * CHUNK;
    f32x4 N0 = *(const f32x4*)(aNxt);
    f32x4 N1 = *(const f32x4*)(aNxt + 4);
    f32x4 N2 = *(const f32x4*)(aNxt + 32);
    f32x4 N3 = *(const f32x4*)(aNxt + 36);

    const unsigned short* sBb = &sB[t & 1][0];
    f32x4 c[4];
#pragma unroll
    for (int nt = 0; nt < 4; ++nt) c[nt] = (f32x4){0.f, 0.f, 0.f, 0.f};

#pragma unroll
    for (int sub = 0; sub < 2; ++sub) {
      fragh Af[2];
      split8h(sub ? A2 : A0, sub ? A3 : A1, Af);

      const int bq = (sub * 4 + g) ^ bkey;
#pragma unroll
      for (int ng = 0; ng < 2; ++ng) {
        fragh Bv[2][2];
#pragma unroll
        for (int nn = 0; nn < 2; ++nn) {
          const int ncol = (ng * 2 + nn) * 16 + ln15;
#pragma unroll
          for (int lvl = 0; lvl < 2; ++lvl)
            Bv[nn][lvl].u =
                *(const u16x8*)(sBb + lvl * 4096 + ncol * 64 + bq * 8);
        }
#pragma unroll
        for (int term = 0; term < 4; ++term)
#pragma unroll
          for (int nn = 0; nn < 2; ++nn) {
            const int nt = ng * 2 + nn;
            c[nt] = __builtin_amdgcn_mfma_f32_16x16x32_f16(
                Af[AI[term]].h, Bv[nn][BI[term]].h, c[nt], 0, 0, 0);
          }
      }
    }
    A0 = N0; A1 = N1; A2 = N2; A3 = N3;

#pragma unroll
    for (int nt = 0; nt < 4; ++nt) {
      macc[nt][0] += (double)c[nt].x;
      macc[nt][1] += (double)c[nt].y;
      macc[nt][2] += (double)c[nt].z;
      macc[nt][3] += (double)c[nt].w;
    }
  }

  // epilogue: D row = g*4 + r (within 16-tile), col = nt*16 + ln15
  if (DIRECT) {
#pragma unroll
    for (int nt = 0; nt < 4; ++nt)
#pragma unroll
      for (int r = 0; r < 4; ++r)
        outg[((size_t)b * NROW + i0 + wv * 16 + g * 4 + r) * NF + nt * 16 + ln15] =
            (macc[nt][r] > THRESH) ? 1.0f : 0.0f;
  } else {
    float* wb = wp + (size_t)z * TOT;
#pragma unroll
    for (int nt = 0; nt < 4; ++nt)
#pragma unroll
      for (int r = 0; r < 4; ++r)
        wb[((size_t)b * NROW + i0 + wv * 16 + g * 4 + r) * NF + nt * 16 + ln15] =
            (float)macc[nt][r];
  }
}

// ---- pass 3: reduce JSPLIT partials in f64, threshold ----
// grid 1024, b = flat&7 == XCD: reads the partial slice its own XCD's gemm
// blocks just wrote (2 MB < 4 MB L2) -> L2-hot instead of HBM re-fetch.
__global__ __launch_bounds__(256)
void combine_thresh(const float* __restrict__ wsv, float* __restrict__ outg) {
  const int flat = blockIdx.x;
  const int b    = flat & 7;
  const int idx  = flat >> 3;                    // 0..127
  const size_t e = ((size_t)b << 17) + (size_t)idx * 1024 + (size_t)threadIdx.x * 4;
  f32x4 p0 = *(const f32x4*)(wsv + e);
  f32x4 p1 = *(const f32x4*)(wsv + e + TOT);
  f32x4 p2 = *(const f32x4*)(wsv + e + 2 * TOT);
  f32x4 p3 = *(const f32x4*)(wsv + e + 3 * TOT);
  f32x4 o;
  o.x = (((double)p0.x + p1.x + p2.x + p3.x) > THRESH) ? 1.0f : 0.0f;
  o.y = (((double)p0.y + p1.y + p2.y + p3.y) > THRESH) ? 1.0f : 0.0f;
  o.z = (((double)p0.z + p1.z + p2.z + p3.z) > THRESH) ? 1.0f : 0.0f;
  o.w = (((double)p0.w + p1.w + p2.w + p3.w) > THRESH) ? 1.0f : 0.0f;
  *(f32x4*)(outg + e) = o;
}

extern "C" void kernel_launch(void* const* d_in, const int* in_sizes, int n_in,
                              void* d_out, int out_size, void* d_ws, size_t ws_size,
                              hipStream_t stream) {
  const float* x = (const float*)d_in[0];
  const float* a = (const float*)d_in[1];
  float* out = (float*)d_out;
  unsigned short* xs = (unsigned short*)d_ws;                 // 4 MB
  float* wp = (float*)((char*)d_ws + 2 * TOT * sizeof(unsigned short));

  prep_x<<<dim3(256), dim3(256), 0, stream>>>(x, xs);

  const size_t need = 2 * TOT * sizeof(unsigned short)
                    + (size_t)JSPLIT * TOT * sizeof(float);   // 20 MB
  if (ws_size >= need) {
    gemm_mfma<false><<<dim3(JSPLIT * BATCH * (NROW / 128)), dim3(512), 0, stream>>>(
        a, xs, out, wp);
    combine_thresh<<<dim3((unsigned)(TOT / 1024)), dim3(256), 0, stream>>>(wp, out);
  } else {
    gemm_mfma<true><<<dim3(BATCH * (NROW / 128)), dim3(512), 0, stream>>>(
        a, xs, out, nullptr);
  }
}